// Round 9
// baseline (159.908 us; speedup 1.0000x reference)
//
#include <hip/hip_runtime.h>

#define H 64
#define NPB 64
typedef short bf16x8 __attribute__((ext_vector_type(8)));
typedef float f32x4 __attribute__((ext_vector_type(4)));

static __device__ __forceinline__ unsigned short f2bf(float f) {
    union { float f; unsigned u; } v; v.f = f;
    unsigned r = v.u + 0x7fffu + ((v.u >> 16) & 1u);
    return (unsigned short)(r >> 16);
}
static __device__ __forceinline__ float bf2f(unsigned short b) {
    union { unsigned u; float f; } v; v.u = ((unsigned)b) << 16;
    return v.f;
}
static __device__ __forceinline__ unsigned pack2bf(float a, float b) {
    return (unsigned)f2bf(a) | ((unsigned)f2bf(b) << 16);
}
static __device__ __forceinline__ void split8(const float* ff, bf16x8& hi, bf16x8& lo) {
#pragma unroll
    for (int j = 0; j < 8; ++j) {
        unsigned short h = f2bf(ff[j]);
        hi[j] = (short)h;
        lo[j] = (short)f2bf(ff[j] - bf2f(h));
    }
}

// ws layout (bytes): dSf [N*4] | gp [256] | v3g [1024] | Wp [65536] | W7p [16384]
// Wp entry idx = (tl*8 + ht*2 + ks)*2 + hl ; each entry = 64 lanes x bf16x8.
// A-frag semantics: lane(c,q) holds W2[tl][h=ht*16+c][k=ks*32+q*8+j], j=0..7.
// W7p entry idx = (ht*2+ks)*2 + hl, same per-lane semantics on W7.

// ---------------------------------------------------------------------------
// Block 0: weight prep (concurrent with edge atomics). Blocks >=1: 8 edges/
// thread, ONE fp32 atomic per edge: T = 4096*deg + S  (T < 2^18).
__global__ __launch_bounds__(256)
void edge_prep_kernel(const int* __restrict__ ei, const float* __restrict__ ew,
                      const float* __restrict__ W1, const float* __restrict__ W2,
                      const float* __restrict__ W3, const float* __restrict__ W4,
                      const float* __restrict__ W7, float* __restrict__ dSf,
                      float* __restrict__ v3g, bf16x8* __restrict__ Wp,
                      bf16x8* __restrict__ W7p, int E) {
    __shared__ float v3s[256];
    const int t = threadIdx.x;
    const int bid = blockIdx.x;

    if (bid == 0) {
        {   // v3[tl][h] = sum_k relu(W4[tl][k]) * W3[tl][h][k]
            int tl = t >> 6, h2 = t & 63;
            const float* __restrict__ w3r = W3 + (tl * H + h2) * H;
            const float* __restrict__ w4r = W4 + tl * H;
            float a0 = 0, a1 = 0, a2 = 0, a3 = 0;
#pragma unroll
            for (int k = 0; k < H; k += 4) {
                a0 += fmaxf(w4r[k + 0], 0.f) * w3r[k + 0];
                a1 += fmaxf(w4r[k + 1], 0.f) * w3r[k + 1];
                a2 += fmaxf(w4r[k + 2], 0.f) * w3r[k + 2];
                a3 += fmaxf(w4r[k + 3], 0.f) * w3r[k + 3];
            }
            v3s[t] = (a0 + a1) + (a2 + a3);
        }
        __syncthreads();
        v3g[t] = v3s[t];
        const int lane = t & 63, set = t >> 6, c = lane & 15, q = lane >> 4;
        // W2 A-frags: 32 combos (tl,ht,ks)
#pragma unroll
        for (int it = 0; it < 8; ++it) {
            int combo = it * 4 + set;
            int tl = combo >> 3, ht = (combo >> 1) & 3, ks = combo & 1;
            const float* __restrict__ wp = W2 + ((tl * 4 + ht) * 16 + c) * 64 + ks * 32 + q * 8;
            float4 f0 = *(const float4*)(wp);
            float4 f1 = *(const float4*)(wp + 4);
            float ff[8] = {f0.x, f0.y, f0.z, f0.w, f1.x, f1.y, f1.z, f1.w};
            bf16x8 hi, lo;
            split8(ff, hi, lo);
            Wp[(combo * 2 + 0) * 64 + lane] = hi;
            Wp[(combo * 2 + 1) * 64 + lane] = lo;
        }
        // W7 A-frags: 8 combos (ht,ks)
#pragma unroll
        for (int it = 0; it < 2; ++it) {
            int combo = it * 4 + set;
            int ht = combo >> 1, ks = combo & 1;
            const float* __restrict__ wp = W7 + (ht * 16 + c) * 64 + ks * 32 + q * 8;
            float4 f0 = *(const float4*)(wp);
            float4 f1 = *(const float4*)(wp + 4);
            float ff[8] = {f0.x, f0.y, f0.z, f0.w, f1.x, f1.y, f1.z, f1.w};
            bf16x8 hi, lo;
            split8(ff, hi, lo);
            W7p[(combo * 2 + 0) * 64 + lane] = hi;
            W7p[(combo * 2 + 1) * 64 + lane] = lo;
        }
        return;
    }

    int probe = ei[2 * (t & 63) + 1];
    bool is64 = (__ballot(probe != 0) == 0ULL);           // wave-uniform
    const int base_e = 8 * ((bid - 1) * 256 + t);
#pragma unroll
    for (int g = 0; g < 2; ++g) {
        int e0 = base_e + 4 * g;
        if (e0 + 3 < E) {
            float4 wv = *(const float4*)(ew + e0);
            int i0, i1, i2, i3;
            if (is64) {
                int4 a = *(const int4*)(ei + 2 * (E + e0));
                int4 b = *(const int4*)(ei + 2 * (E + e0) + 4);
                i0 = a.x; i1 = a.z; i2 = b.x; i3 = b.z;
            } else {
                int4 a = *(const int4*)(ei + E + e0);
                i0 = a.x; i1 = a.y; i2 = a.z; i3 = a.w;
            }
            unsafeAtomicAdd(&dSf[i0], 4096.0f + wv.x);
            unsafeAtomicAdd(&dSf[i1], 4096.0f + wv.y);
            unsafeAtomicAdd(&dSf[i2], 4096.0f + wv.z);
            unsafeAtomicAdd(&dSf[i3], 4096.0f + wv.w);
        } else {
            for (int j = 0; j < 4 && e0 + j < E; ++j) {
                int e = e0 + j;
                int idx = is64 ? ei[2 * (E + e)] : ei[E + e];
                unsafeAtomicAdd(&dSf[idx], 4096.0f + ew[e]);
            }
        }
    }
}

// ---------------------------------------------------------------------------
// One wave = 16 nodes, ALL state in registers. Per layer: 16 MFMA (A=weights
// hi/lo, B=mu^T), fp32 epilogue, then D->B relayout via shuffles with
// COMPILE-TIME register indices (fetch both ht candidates, select by q>>1).
__global__ __launch_bounds__(256, 4)
void node_kernel(const float* __restrict__ mu, const float* __restrict__ x,
                 const float* __restrict__ W1, const float* __restrict__ W5,
                 const float* __restrict__ v3g, const bf16x8* __restrict__ Wp,
                 const bf16x8* __restrict__ W7p, const float* __restrict__ dSf,
                 float* __restrict__ gp, float* __restrict__ out, int N) {
    __shared__ float gpr[4 * 64];

    const int t = threadIdx.x;
    const int lane = t & 63;
    const int wv = __builtin_amdgcn_readfirstlane(t >> 6);
    const int c = lane & 15;
    const int q = lane >> 4;
    const int node = blockIdx.x * NPB + wv * 16 + c;
    const bool valid = node < N;

    float dg = 0.f, sv = 0.f, xv = 0.f;
    if (valid) {
        float T = dSf[node];
        dg = floorf(T * (1.0f / 4096.0f));
        sv = T - 4096.0f * dg;
        xv = x[node];
    }

    // initial B = (dg * mu[node])^T frags: lane(c,q) holds B[k=s*32+q*8+j][n=c]
    bf16x8 B0, B1;
    {
        float ff0[8] = {0,0,0,0,0,0,0,0}, ff1[8] = {0,0,0,0,0,0,0,0};
        if (valid) {
            const float* __restrict__ mp = mu + (size_t)node * H + q * 8;
            float4 a0 = *(const float4*)(mp);
            float4 a1 = *(const float4*)(mp + 4);
            float4 b0 = *(const float4*)(mp + 32);
            float4 b1 = *(const float4*)(mp + 36);
            float t0[8] = {a0.x, a0.y, a0.z, a0.w, a1.x, a1.y, a1.z, a1.w};
            float t1[8] = {b0.x, b0.y, b0.z, b0.w, b1.x, b1.y, b1.z, b1.w};
#pragma unroll
            for (int j = 0; j < 8; ++j) { ff0[j] = t0[j] * dg; ff1[j] = t1[j] * dg; }
        }
#pragma unroll
        for (int j = 0; j < 8; ++j) { B0[j] = (short)f2bf(ff0[j]); B1[j] = (short)f2bf(ff1[j]); }
    }

    unsigned pk[4][2];                       // pk[ht][p]: h=ht*16+q*4+{2p,2p+1}
    const int lo_lane = 32 * (q & 1) + c;    // source lane for j<4 (j>=4: +16)
    const bool hsel = ((q >> 1) != 0);       // dest-side ht select within pair

#pragma unroll
    for (int tl = 0; tl < 4; ++tl) {
        f32x4 acc[4];
#pragma unroll
        for (int ht = 0; ht < 4; ++ht) {
            const int e0 = (tl * 8 + ht * 2) * 2;
            bf16x8 h0 = Wp[(e0 + 0) * 64 + lane];
            bf16x8 l0 = Wp[(e0 + 1) * 64 + lane];
            bf16x8 h1 = Wp[(e0 + 2) * 64 + lane];
            bf16x8 l1 = Wp[(e0 + 3) * 64 + lane];
            f32x4 a = {0.f, 0.f, 0.f, 0.f};
            a = __builtin_amdgcn_mfma_f32_16x16x32_bf16(h0, B0, a, 0, 0, 0);
            a = __builtin_amdgcn_mfma_f32_16x16x32_bf16(l0, B0, a, 0, 0, 0);
            a = __builtin_amdgcn_mfma_f32_16x16x32_bf16(h1, B1, a, 0, 0, 0);
            a = __builtin_amdgcn_mfma_f32_16x16x32_bf16(l1, B1, a, 0, 0, 0);
            acc[ht] = a;
        }
        const bool scale = (tl < 3);
#pragma unroll
        for (int ht = 0; ht < 4; ++ht) {
            float4 w1f = *(const float4*)(W1 + tl * 64 + ht * 16 + q * 4);
            float4 v3f = *(const float4*)(v3g + tl * 64 + ht * 16 + q * 4);
            float v0 = fmaxf(xv * w1f.x + acc[ht][0] + sv * v3f.x, 0.f);
            float v1 = fmaxf(xv * w1f.y + acc[ht][1] + sv * v3f.y, 0.f);
            float v2 = fmaxf(xv * w1f.z + acc[ht][2] + sv * v3f.z, 0.f);
            float v3 = fmaxf(xv * w1f.w + acc[ht][3] + sv * v3f.w, 0.f);
            if (scale) { v0 *= dg; v1 *= dg; v2 *= dg; v3 *= dg; }
            pk[ht][0] = pack2bf(v0, v1);
            pk[ht][1] = pack2bf(v2, v3);
        }
        // D -> next-B relayout. Dest(c,q) B_s.u[p] = pk[s*2+(q>>1)][p&1] taken
        // from lane lo_lane + (p>>1)*16. Register indices in the shuffled
        // expression MUST be uniform -> fetch both candidates, cndmask.
        {
            union { unsigned u[4]; bf16x8 v; } cv;
            unsigned a0 = (unsigned)__shfl((int)pk[0][0], lo_lane);
            unsigned b0 = (unsigned)__shfl((int)pk[1][0], lo_lane);
            unsigned a1 = (unsigned)__shfl((int)pk[0][1], lo_lane);
            unsigned b1 = (unsigned)__shfl((int)pk[1][1], lo_lane);
            unsigned a2 = (unsigned)__shfl((int)pk[0][0], lo_lane + 16);
            unsigned b2 = (unsigned)__shfl((int)pk[1][0], lo_lane + 16);
            unsigned a3 = (unsigned)__shfl((int)pk[0][1], lo_lane + 16);
            unsigned b3 = (unsigned)__shfl((int)pk[1][1], lo_lane + 16);
            cv.u[0] = hsel ? b0 : a0;
            cv.u[1] = hsel ? b1 : a1;
            cv.u[2] = hsel ? b2 : a2;
            cv.u[3] = hsel ? b3 : a3;
            B0 = cv.v;
            a0 = (unsigned)__shfl((int)pk[2][0], lo_lane);
            b0 = (unsigned)__shfl((int)pk[3][0], lo_lane);
            a1 = (unsigned)__shfl((int)pk[2][1], lo_lane);
            b1 = (unsigned)__shfl((int)pk[3][1], lo_lane);
            a2 = (unsigned)__shfl((int)pk[2][0], lo_lane + 16);
            b2 = (unsigned)__shfl((int)pk[3][0], lo_lane + 16);
            a3 = (unsigned)__shfl((int)pk[2][1], lo_lane + 16);
            b3 = (unsigned)__shfl((int)pk[3][1], lo_lane + 16);
            cv.u[0] = hsel ? b0 : a0;
            cv.u[1] = hsel ? b1 : a1;
            cv.u[2] = hsel ? b2 : a2;
            cv.u[3] = hsel ? b3 : a3;
            B1 = cv.v;
        }
    }

    // W7 GEMM + per-node epilogue: pn = sum_h relu(P[h][n]) * W5[64+h]
    {
        f32x4 acc[4];
#pragma unroll
        for (int ht = 0; ht < 4; ++ht) {
            const int e0 = (ht * 2) * 2;
            bf16x8 h0 = W7p[(e0 + 0) * 64 + lane];
            bf16x8 l0 = W7p[(e0 + 1) * 64 + lane];
            bf16x8 h1 = W7p[(e0 + 2) * 64 + lane];
            bf16x8 l1 = W7p[(e0 + 3) * 64 + lane];
            f32x4 a = {0.f, 0.f, 0.f, 0.f};
            a = __builtin_amdgcn_mfma_f32_16x16x32_bf16(h0, B0, a, 0, 0, 0);
            a = __builtin_amdgcn_mfma_f32_16x16x32_bf16(l0, B0, a, 0, 0, 0);
            a = __builtin_amdgcn_mfma_f32_16x16x32_bf16(h1, B1, a, 0, 0, 0);
            a = __builtin_amdgcn_mfma_f32_16x16x32_bf16(l1, B1, a, 0, 0, 0);
            acc[ht] = a;
        }
        float pn = 0.f;
#pragma unroll
        for (int ht = 0; ht < 4; ++ht) {
            float4 w5f = *(const float4*)(W5 + 64 + ht * 16 + q * 4);
            pn += fmaxf(acc[ht][0], 0.f) * w5f.x;
            pn += fmaxf(acc[ht][1], 0.f) * w5f.y;
            pn += fmaxf(acc[ht][2], 0.f) * w5f.z;
            pn += fmaxf(acc[ht][3], 0.f) * w5f.w;
        }
        pn += __shfl_xor(pn, 16);
        pn += __shfl_xor(pn, 32);
        if (valid && q == 0) out[node] = pn;
    }

    // graph pool: sum final mu over this wave's 16 nodes (pk holds final mu)
#pragma unroll
    for (int ht = 0; ht < 4; ++ht) {
#pragma unroll
        for (int r = 0; r < 4; ++r) {
            float m = bf2f((unsigned short)(pk[ht][r >> 1] >> ((r & 1) * 16)));
            m += __shfl_xor(m, 1);
            m += __shfl_xor(m, 2);
            m += __shfl_xor(m, 4);
            m += __shfl_xor(m, 8);
            if (c == 0) gpr[wv * 64 + ht * 16 + q * 4 + r] = m;
        }
    }
    __syncthreads();
    if (t < 64) {
        float g = gpr[t] + gpr[64 + t] + gpr[128 + t] + gpr[192 + t];
        unsafeAtomicAdd(&gp[t], g);
    }
}

// ---------------------------------------------------------------------------
__global__ __launch_bounds__(256)
void finalize_kernel(const float* __restrict__ gp, const float* __restrict__ W5,
                     float* __restrict__ out, int N) {
    int lane = threadIdx.x & 63;
    float v = fmaxf(gp[lane], 0.f) * W5[lane];
    v += __shfl_xor(v, 1);
    v += __shfl_xor(v, 2);
    v += __shfl_xor(v, 4);
    v += __shfl_xor(v, 8);
    v += __shfl_xor(v, 16);
    v += __shfl_xor(v, 32);
    int n = blockIdx.x * blockDim.x + threadIdx.x;
    if (n < N) out[n] += v;
}

// ---------------------------------------------------------------------------
extern "C" void kernel_launch(void* const* d_in, const int* in_sizes, int n_in,
                              void* d_out, int out_size, void* d_ws, size_t ws_size,
                              hipStream_t stream) {
    const float* mu = (const float*)d_in[0];
    const float* x  = (const float*)d_in[1];
    const int*   ei = (const int*)d_in[2];
    const float* ew = (const float*)d_in[3];
    const float* W1 = (const float*)d_in[4];
    const float* W2 = (const float*)d_in[5];
    const float* W3 = (const float*)d_in[6];
    const float* W4 = (const float*)d_in[7];
    const float* W5 = (const float*)d_in[8];
    const float* W7 = (const float*)d_in[9];
    float* out = (float*)d_out;

    const int N = in_sizes[1];
    const int E = in_sizes[3];

    char* ws = (char*)d_ws;
    float*  dSf = (float*)ws;                                   // N*4
    float*  gp  = (float*)(ws + (size_t)N * 4);                 // 256 B
    float*  v3g = (float*)(ws + (size_t)N * 4 + 256);           // 1024 B
    bf16x8* Wp  = (bf16x8*)(ws + (size_t)N * 4 + 1280);         // 65536 B
    bf16x8* W7p = (bf16x8*)(ws + (size_t)N * 4 + 1280 + 65536); // 16384 B

    hipMemsetAsync(ws, 0, (size_t)N * 4 + 256, stream);

    int nb_e = 1 + (E + 8 * 256 - 1) / (8 * 256);
    edge_prep_kernel<<<nb_e, 256, 0, stream>>>(ei, ew, W1, W2, W3, W4, W7,
                                               dSf, v3g, Wp, W7p, E);
    node_kernel<<<(N + NPB - 1) / NPB, 256, 0, stream>>>(mu, x, W1, W5, v3g,
                                                         Wp, W7p, dSf, gp, out, N);
    finalize_kernel<<<(N + 255) / 256, 256, 0, stream>>>(gp, W5, out, N);
}